// Round 5
// baseline (199.203 us; speedup 1.0000x reference)
//
#include <hip/hip_runtime.h>
#include <math.h>

// ===== R5: MEASUREMENT PROBE =====
// attn_partial is launched 3x (idempotent). dur_us - 183.3 = 2 * Kp_warm.
// Kernels otherwise identical to R4.

// Problem constants (match reference)
constexpr int kB  = 8;
constexpr int kHQ = 32;
constexpr int kHK = 8;
constexpr int kD  = 64;
constexpr int kG  = 4;     // Hq/Hk
constexpr int kS  = 32;    // block_seq_stride
constexpr int kNB = 128;   // pages per sequence
constexpr int kT  = 4096;
constexpr int kW  = 1024;  // sliding window
constexpr int kC  = 128;   // chunk of window per block
constexpr int kNC = 8;     // kW / kC
constexpr unsigned kKVoff = (unsigned)(kHK * kS * kD);  // 16384 floats between V-row and K-row

// workspace layout per (bk, c): [G m][G l][G*D o] floats
constexpr int kPartStride = kG + kG + kG * kD;  // 264

__device__ __forceinline__ float wave_reduce_max(float x) {
#pragma unroll
    for (int o = 32; o > 0; o >>= 1) x = fmaxf(x, __shfl_xor(x, o));
    return x;
}
__device__ __forceinline__ float wave_reduce_sum(float x) {
#pragma unroll
    for (int o = 32; o > 0; o >>= 1) x += __shfl_xor(x, o);
    return x;
}

// One block per (b, k, chunk). 256 threads = 4 waves.
__global__ __launch_bounds__(256) void attn_partial(
    const float* __restrict__ q,         // [B,1,HQ,D]
    const float* __restrict__ k_last,    // [B,1,HK,D]
    const float* __restrict__ v_last,    // [B,1,HK,D]
    const float* __restrict__ cache,     // [P,2,HK,S,D]
    const int*   __restrict__ seq_ids,   // [B,NB]
    const int*   __restrict__ start_pos, // [B]
    float*       __restrict__ part)      // [B*HK*NC][kPartStride]
{
    const int tid = threadIdx.x;
    const int c   = blockIdx.x & (kNC - 1);
    const int bk  = blockIdx.x >> 3;
    const int k   = bk & (kHK - 1);
    const int b   = bk >> 3;

    __shared__ __align__(16) float q_lds[kG][kD];        // 1 KB
    __shared__ float    w_lds[kG][kC];                   // 2 KB
    __shared__ unsigned vbase_lds[kC];                   // 512 B: float-index of V row per position
    __shared__ __align__(16) float o_red[16][kG][kD];    // 16 KB: wave*4+r partials
    __shared__ float    redm[4][kG], redl[4][kG];
    __shared__ float    wpos_lds[kG];

    const int pos    = start_pos[b];
    const int t0     = max(0, pos - (kW - 1));
    const int tstart = t0 + c * kC;
    const size_t base = (size_t)(bk * kNC + c) * kPartStride;

    const int gq = tid >> 6, dq = tid & 63;

    // Fully-invalid chunk (short-window cases): write neutral partials and bail.
    if (tstart > pos) {
        if (tid < kG) { part[base + tid] = -1e30f; part[base + kG + tid] = 0.f; }
        part[base + 2 * kG + (gq << 6) + dq] = 0.f;
        return;
    }

    // ---- stage q and per-position V-row offsets ----
    q_lds[gq][dq] = q[(b * kHQ + k * kG + gq) * kD + dq];
    if (tid < kC) {
        const int t    = tstart + tid;                  // t <= pos <= 4095: in bounds
        const int page = seq_ids[b * kNB + (t >> 5)];
        vbase_lds[tid] = (unsigned)(((((unsigned)page * 2u + 1u) * kHK + k) * kS + (t & 31)) * kD);
    }
    __syncthreads();

    // ---- QK^T: 2 lanes per position, half K-row each ----
    const int wave = tid >> 6, lane = tid & 63;
    const int p    = wave * 32 + (lane & 31);           // position within chunk
    const int h    = lane >> 5;                         // which half of the row
    const int t    = tstart + p;
    const bool valid = (t <= pos);

    float accq[kG] = {0.f, 0.f, 0.f, 0.f};
    if (valid) {
        const float* kptr = (t == pos)
            ? k_last + (b * kHK + k) * kD + h * 32
            : cache + (vbase_lds[p] - kKVoff) + h * 32;
        float4 kv[8];
#pragma unroll
        for (int j = 0; j < 8; ++j) kv[j] = ((const float4*)kptr)[j];
#pragma unroll
        for (int g = 0; g < kG; ++g) {
            float a = 0.f;
#pragma unroll
            for (int j = 0; j < 8; ++j) {
                const float4 qv = ((const float4*)&q_lds[g][0])[h * 8 + j];
                a += qv.x * kv[j].x + qv.y * kv[j].y + qv.z * kv[j].z + qv.w * kv[j].w;
            }
            accq[g] += a;
        }
    }
    float sc[kG];
#pragma unroll
    for (int g = 0; g < kG; ++g) {
        const float s = accq[g] + __shfl_xor(accq[g], 32);
        sc[g] = valid ? s * 0.125f : -1e30f;            // 1/sqrt(64)
    }

    // ---- block max per head ----
    float m[kG];
#pragma unroll
    for (int g = 0; g < kG; ++g) m[g] = wave_reduce_max(sc[g]);
    if (lane == 0) {
#pragma unroll
        for (int g = 0; g < kG; ++g) redm[wave][g] = m[g];
    }
    __syncthreads();
#pragma unroll
    for (int g = 0; g < kG; ++g)
        m[g] = fmaxf(fmaxf(redm[0][g], redm[1][g]), fmaxf(redm[2][g], redm[3][g]));

    // ---- weights + block sum (h==0 lanes only, to avoid double count) ----
    float wv[kG], ls[kG];
#pragma unroll
    for (int g = 0; g < kG; ++g) {
        wv[g] = valid ? __expf(sc[g] - m[g]) : 0.f;
        if (h == 0) w_lds[g][p] = wv[g];
        ls[g] = wave_reduce_sum(h ? 0.f : wv[g]);
    }
    if (lane == 0) {
#pragma unroll
        for (int g = 0; g < kG; ++g) redl[wave][g] = ls[g];
    }
    __syncthreads();

    if (tid < kG) {
        part[base + tid]      = m[tid];
        part[base + kG + tid] = redl[0][tid] + redl[1][tid] + redl[2][tid] + redl[3][tid];
        // pull the new-token weight out of the streamed PV loop
        const int ppos = pos - tstart;                  // >= 0 here
        float wp = 0.f;
        if (ppos < kC) { wp = w_lds[tid][ppos]; w_lds[tid][ppos] = 0.f; }
        wpos_lds[tid] = wp;
    }
    __syncthreads();

    // ---- PV: wave <-> 32-position slice; 4 rows per load instruction ----
    // lane -> (row-in-group r = lane>>4, d-quad dl = (lane&15)*4)
    const int r  = lane >> 4;
    const int dl = (lane & 15) << 2;
    float4 accv[kG] = {};
    const int pbase  = wave * 32;
    const int nvalid = (pos - tstart + 1) - pbase;
    if (nvalid > 0) {
        // all 8 loads independent & unconditional: overrun rows have w==0, addresses safe
#pragma unroll
        for (int i = 0; i < 32; i += 4) {
            const int pp = pbase + i + r;
            const float4 vv = *(const float4*)(cache + (size_t)vbase_lds[pp] + dl);
#pragma unroll
            for (int g = 0; g < kG; ++g) {
                const float w = w_lds[g][pp];
                accv[g].x = fmaf(w, vv.x, accv[g].x);
                accv[g].y = fmaf(w, vv.y, accv[g].y);
                accv[g].z = fmaf(w, vv.z, accv[g].z);
                accv[g].w = fmaf(w, vv.w, accv[g].w);
            }
        }
    }
    {
        const int slot = (wave << 2) + r;
#pragma unroll
        for (int g = 0; g < kG; ++g)
            ((float4*)&o_red[slot][g][0])[lane & 15] = accv[g];
    }
    __syncthreads();

    // ---- 16-slot reduce + new-token V contribution ----
    float o = wpos_lds[gq] * v_last[(b * kHK + k) * kD + dq];
#pragma unroll
    for (int s = 0; s < 16; ++s) o += o_red[s][gq][dq];
    part[base + 2 * kG + (gq << 6) + dq] = o;
}

// One block per (b,k). 256 threads <-> (g,d). Merge chunks + sink.
__global__ __launch_bounds__(256) void attn_combine(
    const float* __restrict__ part,
    const float* __restrict__ sink,  // [HQ]
    float*       __restrict__ out)   // [B,1,HQ,D]
{
    const int tid = threadIdx.x;
    const int bk  = blockIdx.x;
    const int k   = bk & (kHK - 1);
    const int b   = bk >> 3;
    const int g   = tid >> 6, d = tid & 63;
    const int h   = k * kG + g;

    const float sk = sink[h];
    float m[kNC], l[kNC];
#pragma unroll
    for (int c = 0; c < kNC; ++c) {
        const size_t base = (size_t)(bk * kNC + c) * kPartStride;
        m[c] = part[base + g];
        l[c] = part[base + kG + g];
    }
    float M = sk;
#pragma unroll
    for (int c = 0; c < kNC; ++c) M = fmaxf(M, m[c]);

    float denom = __expf(sk - M);  // sink contributes to denominator only
    float numer = 0.f;
#pragma unroll
    for (int c = 0; c < kNC; ++c) {
        const size_t base = (size_t)(bk * kNC + c) * kPartStride;
        const float  f    = (m[c] > -1e29f) ? __expf(m[c] - M) : 0.f;
        denom += f * l[c];
        numer  = fmaf(f, part[base + 2 * kG + (g << 6) + d], numer);
    }
    out[(b * kHQ + h) * kD + d] = numer / denom;
}

extern "C" void kernel_launch(void* const* d_in, const int* in_sizes, int n_in,
                              void* d_out, int out_size, void* d_ws, size_t ws_size,
                              hipStream_t stream) {
    const float* q     = (const float*)d_in[0];
    const float* klast = (const float*)d_in[1];
    const float* vlast = (const float*)d_in[2];
    const float* cache = (const float*)d_in[3];
    const int*   sbi   = (const int*)d_in[4];
    const int*   spos  = (const int*)d_in[5];
    const float* sink  = (const float*)d_in[6];
    float*       out   = (float*)d_out;
    float*       part  = (float*)d_ws;  // 64 * 8 * 264 * 4B = 540 KB

    // PROBE: 3 identical launches of attn_partial (idempotent writes).
    // dur_us - 183.3 = 2 * Kp_warm.
    hipLaunchKernelGGL(attn_partial, dim3(kB * kHK * kNC), dim3(256), 0, stream,
                       q, klast, vlast, cache, sbi, spos, part);
    hipLaunchKernelGGL(attn_partial, dim3(kB * kHK * kNC), dim3(256), 0, stream,
                       q, klast, vlast, cache, sbi, spos, part);
    hipLaunchKernelGGL(attn_partial, dim3(kB * kHK * kNC), dim3(256), 0, stream,
                       q, klast, vlast, cache, sbi, spos, part);
    hipLaunchKernelGGL(attn_combine, dim3(kB * kHK), dim3(256), 0, stream,
                       part, sink, out);
}

// Round 6
// 180.382 us; speedup vs baseline: 1.1043x; 1.1043x over previous
//
#include <hip/hip_runtime.h>
#include <math.h>

// Problem constants (match reference)
constexpr int kB  = 8;
constexpr int kHQ = 32;
constexpr int kHK = 8;
constexpr int kD  = 64;
constexpr int kG  = 4;     // Hq/Hk
constexpr int kS  = 32;    // block_seq_stride
constexpr int kNB = 128;   // pages per sequence
constexpr int kT  = 4096;
constexpr int kW  = 1024;  // sliding window
constexpr int kC  = 64;    // chunk of window per block
constexpr int kNC = 16;    // kW / kC
constexpr unsigned kKVoff = (unsigned)(kHK * kS * kD);  // 16384 floats between V-row and K-row

// workspace layout per (bk, c): [G m][G l][G*D o] floats
constexpr int kPartStride = kG + kG + kG * kD;  // 264

__device__ __forceinline__ float wave_reduce_max(float x) {
#pragma unroll
    for (int o = 32; o > 0; o >>= 1) x = fmaxf(x, __shfl_xor(x, o));
    return x;
}
__device__ __forceinline__ float wave_reduce_sum(float x) {
#pragma unroll
    for (int o = 32; o > 0; o >>= 1) x += __shfl_xor(x, o);
    return x;
}

// One block per (b, k, chunk). 256 threads = 4 waves, chunk = 64 positions.
__global__ __launch_bounds__(256) void attn_partial(
    const float* __restrict__ q,         // [B,1,HQ,D]
    const float* __restrict__ k_last,    // [B,1,HK,D]
    const float* __restrict__ v_last,    // [B,1,HK,D]
    const float* __restrict__ cache,     // [P,2,HK,S,D]
    const int*   __restrict__ seq_ids,   // [B,NB]
    const int*   __restrict__ start_pos, // [B]
    float*       __restrict__ part)      // [B*HK*NC][kPartStride]
{
    const int tid = threadIdx.x;
    const int c   = blockIdx.x & (kNC - 1);
    const int bk  = blockIdx.x >> 4;
    const int k   = bk & (kHK - 1);
    const int b   = bk >> 3;

    __shared__ __align__(16) float q_lds[kG][kD];        // 1 KB
    __shared__ float    w_lds[kG][kC];                   // 1 KB
    __shared__ unsigned vbase_lds[kC];                   // 256 B
    __shared__ __align__(16) float o_red[16][kG][kD];    // 16 KB
    __shared__ float    redm[4][kG], redl[4][kG];
    __shared__ float    wpos_lds[kG];

    const int pos    = start_pos[b];
    const int t0     = max(0, pos - (kW - 1));
    const int tstart = t0 + c * kC;
    const size_t base = (size_t)(bk * kNC + c) * kPartStride;

    const int gq = tid >> 6, dq = tid & 63;

    // Fully-invalid chunk (short-window cases): write neutral partials and bail.
    if (tstart > pos) {
        if (tid < kG) { part[base + tid] = -1e30f; part[base + kG + tid] = 0.f; }
        part[base + 2 * kG + (gq << 6) + dq] = 0.f;
        return;
    }

    // ---- stage q and per-position V-row offsets ----
    q_lds[gq][dq] = q[(b * kHQ + k * kG + gq) * kD + dq];
    if (tid < kC) {
        const int t    = tstart + tid;   // t <= t0+1023 <= pos <= 4095: in bounds
        const int page = seq_ids[b * kNB + (t >> 5)];
        vbase_lds[tid] = (unsigned)(((((unsigned)page * 2u + 1u) * kHK + k) * kS + (t & 31)) * kD);
    }
    __syncthreads();

    // ---- QK^T: 4 lanes per position, quarter K-row each ----
    const int wave = tid >> 6, lane = tid & 63;
    const int p    = wave * 16 + (lane & 15);           // position within chunk
    const int qtr  = lane >> 4;                         // which quarter of the row
    const int t    = tstart + p;
    const bool valid = (t <= pos);

    float accq[kG] = {0.f, 0.f, 0.f, 0.f};
    if (valid) {
        const float* kptr = (t == pos)
            ? k_last + (b * kHK + k) * kD + qtr * 16
            : cache + (vbase_lds[p] - kKVoff) + qtr * 16;
        float4 kv[4];
#pragma unroll
        for (int j = 0; j < 4; ++j) kv[j] = ((const float4*)kptr)[j];
#pragma unroll
        for (int g = 0; g < kG; ++g) {
            float a = 0.f;
#pragma unroll
            for (int j = 0; j < 4; ++j) {
                const float4 qv = ((const float4*)&q_lds[g][0])[qtr * 4 + j];
                a += qv.x * kv[j].x + qv.y * kv[j].y + qv.z * kv[j].z + qv.w * kv[j].w;
            }
            accq[g] += a;
        }
    }
    float sc[kG];
#pragma unroll
    for (int g = 0; g < kG; ++g) {
        float s = accq[g] + __shfl_xor(accq[g], 16);
        s += __shfl_xor(s, 32);
        sc[g] = valid ? s * 0.125f : -1e30f;            // 1/sqrt(64)
    }

    // ---- block max per head ----
    float m[kG];
#pragma unroll
    for (int g = 0; g < kG; ++g) m[g] = wave_reduce_max(sc[g]);
    if (lane == 0) {
#pragma unroll
        for (int g = 0; g < kG; ++g) redm[wave][g] = m[g];
    }
    __syncthreads();
#pragma unroll
    for (int g = 0; g < kG; ++g)
        m[g] = fmaxf(fmaxf(redm[0][g], redm[1][g]), fmaxf(redm[2][g], redm[3][g]));

    // ---- weights + block sum (qtr==0 lanes only, to avoid quadruple count) ----
    float wv[kG], ls[kG];
#pragma unroll
    for (int g = 0; g < kG; ++g) {
        wv[g] = valid ? __expf(sc[g] - m[g]) : 0.f;
        if (qtr == 0) w_lds[g][p] = wv[g];
        ls[g] = wave_reduce_sum(qtr ? 0.f : wv[g]);
    }
    if (lane == 0) {
#pragma unroll
        for (int g = 0; g < kG; ++g) redl[wave][g] = ls[g];
    }
    __syncthreads();

    if (tid < kG) {
        part[base + tid]      = m[tid];
        part[base + kG + tid] = redl[0][tid] + redl[1][tid] + redl[2][tid] + redl[3][tid];
        // pull the new-token weight out of the streamed PV loop
        const int ppos = pos - tstart;                  // >= 0 here
        float wp = 0.f;
        if (ppos < kC) { wp = w_lds[tid][ppos]; w_lds[tid][ppos] = 0.f; }
        wpos_lds[tid] = wp;
    }
    __syncthreads();

    // ---- PV: wave <-> 16-position slice; 4 rows per load instruction ----
    const int r  = lane >> 4;          // row within 4-row group
    const int dl = (lane & 15) << 2;   // d-quad
    float4 accv[kG] = {};
    const int pbase  = wave * 16;
    const int nvalid = (pos - tstart + 1) - pbase;
    if (nvalid > 0) {
        // 4 independent unconditional loads: overrun rows have w==0, addresses safe
#pragma unroll
        for (int i = 0; i < 16; i += 4) {
            const int pp = pbase + i + r;
            const float4 vv = *(const float4*)(cache + (size_t)vbase_lds[pp] + dl);
#pragma unroll
            for (int g = 0; g < kG; ++g) {
                const float w = w_lds[g][pp];
                accv[g].x = fmaf(w, vv.x, accv[g].x);
                accv[g].y = fmaf(w, vv.y, accv[g].y);
                accv[g].z = fmaf(w, vv.z, accv[g].z);
                accv[g].w = fmaf(w, vv.w, accv[g].w);
            }
        }
    }
    {
        const int slot = (wave << 2) + r;
#pragma unroll
        for (int g = 0; g < kG; ++g)
            ((float4*)&o_red[slot][g][0])[lane & 15] = accv[g];
    }
    __syncthreads();

    // ---- 16-slot reduce + new-token V contribution ----
    float o = wpos_lds[gq] * v_last[(b * kHK + k) * kD + dq];
#pragma unroll
    for (int s = 0; s < 16; ++s) o += o_red[s][gq][dq];
    part[base + 2 * kG + (gq << 6) + dq] = o;
}

// One block per (b,k). 256 threads <-> (g,d). Merge chunks + sink.
__global__ __launch_bounds__(256) void attn_combine(
    const float* __restrict__ part,
    const float* __restrict__ sink,  // [HQ]
    float*       __restrict__ out)   // [B,1,HQ,D]
{
    const int tid = threadIdx.x;
    const int bk  = blockIdx.x;
    const int k   = bk & (kHK - 1);
    const int b   = bk >> 3;
    const int g   = tid >> 6, d = tid & 63;
    const int h   = k * kG + g;

    const float sk = sink[h];
    float m[kNC], l[kNC];
#pragma unroll
    for (int c = 0; c < kNC; ++c) {
        const size_t base = (size_t)(bk * kNC + c) * kPartStride;
        m[c] = part[base + g];
        l[c] = part[base + kG + g];
    }
    float M = sk;
#pragma unroll
    for (int c = 0; c < kNC; ++c) M = fmaxf(M, m[c]);

    float denom = __expf(sk - M);  // sink contributes to denominator only
    float numer = 0.f;
#pragma unroll
    for (int c = 0; c < kNC; ++c) {
        const size_t base = (size_t)(bk * kNC + c) * kPartStride;
        const float  f    = (m[c] > -1e29f) ? __expf(m[c] - M) : 0.f;
        denom += f * l[c];
        numer  = fmaf(f, part[base + 2 * kG + (g << 6) + d], numer);
    }
    out[(b * kHQ + h) * kD + d] = numer / denom;
}

extern "C" void kernel_launch(void* const* d_in, const int* in_sizes, int n_in,
                              void* d_out, int out_size, void* d_ws, size_t ws_size,
                              hipStream_t stream) {
    const float* q     = (const float*)d_in[0];
    const float* klast = (const float*)d_in[1];
    const float* vlast = (const float*)d_in[2];
    const float* cache = (const float*)d_in[3];
    const int*   sbi   = (const int*)d_in[4];
    const int*   spos  = (const int*)d_in[5];
    const float* sink  = (const float*)d_in[6];
    float*       out   = (float*)d_out;
    float*       part  = (float*)d_ws;  // 64 * 16 * 264 * 4B = 1.08 MB

    hipLaunchKernelGGL(attn_partial, dim3(kB * kHK * kNC), dim3(256), 0, stream,
                       q, klast, vlast, cache, sbi, spos, part);
    hipLaunchKernelGGL(attn_combine, dim3(kB * kHK), dim3(256), 0, stream,
                       part, sink, out);
}